// Round 4
// baseline (446.401 us; speedup 1.0000x reference)
//
#include <hip/hip_runtime.h>
#include <hip/hip_bf16.h>
#include <math.h>

#define A_TOK 4096
#define DDIM  1024
#define NEXP  8
#define FDIM  2816

typedef __bf16 bf16_t;
typedef __bf16 bf16x8 __attribute__((ext_vector_type(8)));
typedef __bf16 bf16x4 __attribute__((ext_vector_type(4)));
typedef float  f32x4  __attribute__((ext_vector_type(4)));

// ======================= workspace layout =======================
//   [0,16384)      int   idx_a[4096]
//   [16384,32768)  float gate_a[4096]
//   [32832,32868)  int   offsets[9]
//   [33280,49664)  int   perm[4096]
static constexpr size_t OFF_XS   = 65536;
static constexpr size_t OFF_XR   = OFF_XS   + (size_t)A_TOK * DDIM * 2;
static constexpr size_t OFF_MIDS = OFF_XR   + (size_t)(A_TOK + 128) * DDIM * 2;
static constexpr size_t OFF_MIDR = OFF_MIDS + (size_t)A_TOK * FDIM * 2;
static constexpr size_t OFF_W1T  = OFF_MIDR + (size_t)(A_TOK + 128) * FDIM * 2;
static constexpr size_t OFF_W3T  = OFF_W1T  + (size_t)NEXP * DDIM * FDIM * 2;
static constexpr size_t OFF_W2T  = OFF_W3T  + (size_t)NEXP * DDIM * FDIM * 2;
static constexpr size_t OFF_WS1T = OFF_W2T  + (size_t)NEXP * DDIM * FDIM * 2;
static constexpr size_t OFF_WS3T = OFF_WS1T + (size_t)DDIM * FDIM * 2;
static constexpr size_t OFF_WS2T = OFF_WS3T + (size_t)DDIM * FDIM * 2;
static constexpr size_t WS_NEED  = OFF_WS2T + (size_t)DDIM * FDIM * 2;   // ~209.5 MiB

// ======================= router: scores =======================
__global__ __launch_bounds__(256)
void score_kernel(const float* __restrict__ x,
                  const float* __restrict__ router,
                  int* __restrict__ idx_a,
                  float* __restrict__ gate_a)
{
    __shared__ float rT[NEXP][DDIM];
    const int tid = threadIdx.x;
    for (int i = tid; i < DDIM * NEXP; i += 256)
        rT[i & 7][i >> 3] = router[i];
    __syncthreads();

    const int wid = tid >> 6, lane = tid & 63;
    const int t = blockIdx.x * 4 + wid;
    const float* xr = x + (size_t)t * DDIM;

    double s[NEXP];
#pragma unroll
    for (int e = 0; e < NEXP; ++e) s[e] = 0.0;
#pragma unroll
    for (int i = 0; i < DDIM / 64; ++i) {
        int d = i * 64 + lane;
        float xv = xr[d];
#pragma unroll
        for (int e = 0; e < NEXP; ++e)
            s[e] += (double)xv * (double)rT[e][d];
    }
#pragma unroll
    for (int e = 0; e < NEXP; ++e) {
#pragma unroll
        for (int off = 32; off > 0; off >>= 1)
            s[e] += __shfl_xor(s[e], off);
    }
    if (lane == 0) {
        int best = 0; double bv = s[0];
#pragma unroll
        for (int e = 1; e < NEXP; ++e)
            if (s[e] > bv) { bv = s[e]; best = e; }
        idx_a[t] = best;
        gate_a[t] = 1.0f / (1.0f + expf(-(float)bv));
    }
}

// ======================= fused count + scan + scatter =======================
__global__ __launch_bounds__(1024)
void perm_kernel(const int* __restrict__ idx_a,
                 int* __restrict__ offsets,
                 int* __restrict__ perm)
{
    __shared__ int cnt[NEXP];
    __shared__ int base[NEXP];
    const int tid = threadIdx.x;
    if (tid < NEXP) cnt[tid] = 0;
    __syncthreads();

    int e[4];
#pragma unroll
    for (int j = 0; j < 4; ++j) {
        e[j] = idx_a[j * 1024 + tid];
        atomicAdd(&cnt[e[j]], 1);
    }
    __syncthreads();
    if (tid == 0) {
        int acc = 0;
#pragma unroll
        for (int k = 0; k < NEXP; ++k) {
            base[k] = acc; offsets[k] = acc; acc += cnt[k];
        }
        offsets[NEXP] = acc;
    }
    __syncthreads();
#pragma unroll
    for (int j = 0; j < 4; ++j) {
        int t = j * 1024 + tid;
        int pos = atomicAdd(&base[e[j]], 1);
        perm[pos] = t;
    }
}

// ======================= prep kernels =======================
__global__ void prep_x_kernel(const float* __restrict__ x,
                              const float* __restrict__ gate_a,
                              const int* __restrict__ perm,
                              bf16_t* __restrict__ xs,
                              bf16_t* __restrict__ xr)
{
    const int p = blockIdx.x;
    const int d = threadIdx.x * 4;
    float4 v = *(const float4*)(x + (size_t)p * DDIM + d);
    bf16x4 o;
    o[0] = (bf16_t)v.x; o[1] = (bf16_t)v.y; o[2] = (bf16_t)v.z; o[3] = (bf16_t)v.w;
    *(bf16x4*)(xs + (size_t)p * DDIM + d) = o;

    const int tok = perm[p];
    const float g = gate_a[tok];
    float4 w = *(const float4*)(x + (size_t)tok * DDIM + d);
    bf16x4 o2;
    o2[0] = (bf16_t)(w.x * g); o2[1] = (bf16_t)(w.y * g);
    o2[2] = (bf16_t)(w.z * g); o2[3] = (bf16_t)(w.w * g);
    *(bf16x4*)(xr + (size_t)p * DDIM + d) = o2;
}

// transpose+convert core: src [R][C] fp32 -> dst [C][R] bf16, one 64x64 tile
__device__ __forceinline__ void tconv_tile(const float* __restrict__ src,
                                           bf16_t* __restrict__ dst,
                                           int R, int C, int r0, int c0)
{
    __shared__ __align__(16) bf16_t t[64][72];
    const int tid = threadIdx.x;
    const int rl = tid >> 4;
    const int cl = (tid & 15) * 4;
#pragma unroll
    for (int i = 0; i < 4; ++i) {
        float4 v = *(const float4*)(src + (size_t)(r0 + rl + i * 16) * C + c0 + cl);
        t[cl + 0][rl + i * 16] = (bf16_t)v.x;
        t[cl + 1][rl + i * 16] = (bf16_t)v.y;
        t[cl + 2][rl + i * 16] = (bf16_t)v.z;
        t[cl + 3][rl + i * 16] = (bf16_t)v.w;
    }
    __syncthreads();
    const int cl2 = tid >> 3;
    const int rl2 = (tid & 7) * 8;
#pragma unroll
    for (int i = 0; i < 2; ++i) {
        int c = cl2 + i * 32;
        bf16x8 vv = *(const bf16x8*)&t[c][rl2];
        *(bf16x8*)(dst + (size_t)(c0 + c) * R + r0 + rl2) = vv;
    }
}

__global__ void tconvA_kernel(const float* __restrict__ w1, const float* __restrict__ w3,
                              const float* __restrict__ ws1, const float* __restrict__ ws3,
                              bf16_t* __restrict__ w1T, bf16_t* __restrict__ w3T,
                              bf16_t* __restrict__ ws1T, bf16_t* __restrict__ ws3T)
{
    const int z = blockIdx.z;
    const size_t ms = (size_t)DDIM * FDIM;
    const float* src; bf16_t* dst;
    if (z < 8)       { src = w1 + (size_t)z * ms;       dst = w1T + (size_t)z * ms; }
    else if (z < 16) { src = w3 + (size_t)(z - 8) * ms; dst = w3T + (size_t)(z - 8) * ms; }
    else if (z == 16){ src = ws1;                        dst = ws1T; }
    else             { src = ws3;                        dst = ws3T; }
    tconv_tile(src, dst, DDIM, FDIM, blockIdx.y * 64, blockIdx.x * 64);
}

__global__ void tconvB_kernel(const float* __restrict__ w2, const float* __restrict__ ws2,
                              bf16_t* __restrict__ w2T, bf16_t* __restrict__ ws2T)
{
    const int z = blockIdx.z;
    const size_t ms = (size_t)DDIM * FDIM;
    const float* src; bf16_t* dst;
    if (z < 8) { src = w2 + (size_t)z * ms; dst = w2T + (size_t)z * ms; }
    else       { src = ws2;                  dst = ws2T; }
    tconv_tile(src, dst, FDIM, DDIM, blockIdx.y * 64, blockIdx.x * 64);
}

// ======================= bf16 GEMM machinery =======================
__device__ __forceinline__ void glds16(const bf16_t* g, bf16_t* l)
{
    __builtin_amdgcn_global_load_lds(
        (const __attribute__((address_space(1))) void*)g,
        (__attribute__((address_space(3))) void*)l, 16, 0, 0);
}

// stage 128 rows x 32 bf16 (64B/row), XOR-swizzled on 16B slots (4 slots/row):
// LDS[row][slot] = global[row][slot ^ (row&3)]
__device__ __forceinline__ void stage32(const bf16_t* __restrict__ src,
                                        size_t stride, bf16_t* lds, int tid)
{
#pragma unroll
    for (int i = 0; i < 2; ++i) {
        int o = i * 256 + tid;          // 16B unit 0..511
        int row = o >> 2;
        int slot = o & 3;
        int srcSlot = slot ^ (row & 3);
        glds16(src + (size_t)row * stride + srcSlot * 8, lds + (size_t)o * 8);
    }
}

// byte offset of fragment (row, k-group kg in [0,4)) in a 128x32 swizzled tile
__device__ __forceinline__ int swz32(int row, int kg)
{
    return row * 64 + ((kg ^ (row & 3)) << 4);
}

// XCD-chunked m-major remap: consecutive hw blocks on one XCD share the B panel.
// total = gridDim.x*gridDim.y must be divisible by 8; MBLK = 32 in both GEMMs.
__device__ __forceinline__ void remap_nm(int& nb, int& mb)
{
    int lin = blockIdx.x + blockIdx.y * gridDim.x;
    int cpx = (gridDim.x * gridDim.y) >> 3;
    int w = (lin & 7) * cpx + (lin >> 3);
    nb = w >> 5;        // w / 32
    mb = w & 31;        // w % 32
}

// GEMM1: mid = silu(A@W1T^T) * (A@W3T^T); 128x128 tile, BK=32, 2-phase dbuf
__global__ __launch_bounds__(256, 2)
void gemm1_bf16(const bf16_t* __restrict__ xr, const bf16_t* __restrict__ xs,
                const bf16_t* __restrict__ w1T, const bf16_t* __restrict__ w3T,
                const bf16_t* __restrict__ ws1T, const bf16_t* __restrict__ ws3T,
                const int* __restrict__ offsets,
                bf16_t* __restrict__ mid_r, bf16_t* __restrict__ mid_s)
{
    int nb, mb;
    remap_nm(nb, mb);
    const int g  = blockIdx.z;
    const int n0 = nb * 128;
    int m0, mEnd;
    const bf16_t *pa, *pw1, *pw3;
    bf16_t* pout;
    if (g < NEXP) {
        int s = offsets[g], e = offsets[g + 1];
        m0 = s + mb * 128;
        if (m0 >= e) return;
        mEnd = e;
        pa = xr;
        pw1 = w1T + (size_t)g * DDIM * FDIM;
        pw3 = w3T + (size_t)g * DDIM * FDIM;
        pout = mid_r;
    } else {
        m0 = mb * 128;
        mEnd = A_TOK;
        pa = xs; pw1 = ws1T; pw3 = ws3T; pout = mid_s;
    }

    __shared__ __align__(16) bf16_t sA[2][128 * 32];
    __shared__ __align__(16) bf16_t sB1[2][128 * 32];
    __shared__ __align__(16) bf16_t sB3[2][128 * 32];

    const int tid  = threadIdx.x;
    const int lane = tid & 63;
    const int wid  = tid >> 6;
    const int wm   = wid >> 1, wn = wid & 1;
    const int fr   = lane & 15;
    const int fq   = lane >> 4;

    f32x4 acc1[4][4], acc3[4][4];
#pragma unroll
    for (int i = 0; i < 4; ++i)
#pragma unroll
        for (int j = 0; j < 4; ++j) {
            acc1[i][j] = (f32x4){0.f, 0.f, 0.f, 0.f};
            acc3[i][j] = (f32x4){0.f, 0.f, 0.f, 0.f};
        }

    const bf16_t* srcA  = pa  + (size_t)m0 * DDIM;
    const bf16_t* srcB1 = pw1 + (size_t)n0 * DDIM;
    const bf16_t* srcB3 = pw3 + (size_t)n0 * DDIM;

#define G1_STAGE(BUF, KT) do {                                   \
        int k0_ = (KT) * 32;                                     \
        stage32(srcA  + k0_, DDIM, sA[BUF],  tid);               \
        stage32(srcB1 + k0_, DDIM, sB1[BUF], tid);               \
        stage32(srcB3 + k0_, DDIM, sB3[BUF], tid);               \
    } while (0)

#define G1_COMPUTE(BUF) do {                                                  \
        bf16x8 af[4], b1f[4], b3f[4];                                         \
        _Pragma("unroll")                                                     \
        for (int mi = 0; mi < 4; ++mi) {                                      \
            int r = wm * 64 + mi * 16 + fr;                                   \
            af[mi] = *(const bf16x8*)((const char*)sA[BUF] + swz32(r, fq));   \
        }                                                                     \
        _Pragma("unroll")                                                     \
        for (int ni = 0; ni < 4; ++ni) {                                      \
            int r = wn * 64 + ni * 16 + fr;                                   \
            b1f[ni] = *(const bf16x8*)((const char*)sB1[BUF] + swz32(r, fq)); \
            b3f[ni] = *(const bf16x8*)((const char*)sB3[BUF] + swz32(r, fq)); \
        }                                                                     \
        _Pragma("unroll")                                                     \
        for (int mi = 0; mi < 4; ++mi)                                        \
            _Pragma("unroll")                                                 \
            for (int ni = 0; ni < 4; ++ni) {                                  \
                acc1[mi][ni] = __builtin_amdgcn_mfma_f32_16x16x32_bf16(       \
                    af[mi], b1f[ni], acc1[mi][ni], 0, 0, 0);                  \
                acc3[mi][ni] = __builtin_amdgcn_mfma_f32_16x16x32_bf16(       \
                    af[mi], b3f[ni], acc3[mi][ni], 0, 0, 0);                  \
            }                                                                 \
    } while (0)

    const int NT = DDIM / 32;          // 32, even
    G1_STAGE(0, 0);
    __syncthreads();
    for (int kt = 0; kt < NT; kt += 2) {
        G1_STAGE(1, kt + 1);           // kt+1 < NT always (NT even)
        G1_COMPUTE(0);
        __syncthreads();
        if (kt + 2 < NT) G1_STAGE(0, kt + 2);
        G1_COMPUTE(1);
        __syncthreads();
    }
#undef G1_STAGE
#undef G1_COMPUTE

#pragma unroll
    for (int mi = 0; mi < 4; ++mi) {
        int prow_b = m0 + wm * 64 + mi * 16 + fq * 4;
#pragma unroll
        for (int r = 0; r < 4; ++r) {
            int prow = prow_b + r;
            if (prow < mEnd) {
#pragma unroll
                for (int ni = 0; ni < 4; ++ni) {
                    float h1 = acc1[mi][ni][r];
                    float h3 = acc3[mi][ni][r];
                    float vv = h1 / (1.0f + __expf(-h1)) * h3;
                    int col = n0 + wn * 64 + ni * 16 + fr;
                    pout[(size_t)prow * FDIM + col] = (bf16_t)vv;
                }
            }
        }
    }
}

// GEMM2: out = mid @ W2; 128x128 tile, BK=32, 2-phase dbuf
template <bool ROUTED>
__global__ __launch_bounds__(256, 2)
void gemm2_bf16(const bf16_t* __restrict__ mid, const bf16_t* __restrict__ w2T,
                const int* __restrict__ perm, const int* __restrict__ offsets,
                float* __restrict__ out)
{
    int nb, mb;
    remap_nm(nb, mb);
    const int n0 = nb * 128;
    int m0, mEnd;
    const bf16_t* pb;
    if (ROUTED) {
        int g = blockIdx.z;
        int s = offsets[g], e = offsets[g + 1];
        m0 = s + mb * 128;
        if (m0 >= e) return;
        mEnd = e;
        pb = w2T + (size_t)g * DDIM * FDIM;
    } else {
        m0 = mb * 128;
        mEnd = A_TOK;
        pb = w2T;
    }

    __shared__ __align__(16) bf16_t sA[2][128 * 32];
    __shared__ __align__(16) bf16_t sB[2][128 * 32];

    const int tid  = threadIdx.x;
    const int lane = tid & 63;
    const int wid  = tid >> 6;
    const int wm   = wid >> 1, wn = wid & 1;
    const int fr   = lane & 15;
    const int fq   = lane >> 4;

    f32x4 acc[4][4];
#pragma unroll
    for (int i = 0; i < 4; ++i)
#pragma unroll
        for (int j = 0; j < 4; ++j)
            acc[i][j] = (f32x4){0.f, 0.f, 0.f, 0.f};

    const bf16_t* srcA = mid + (size_t)m0 * FDIM;
    const bf16_t* srcB = pb  + (size_t)n0 * FDIM;

#define G2_STAGE(BUF, KT) do {                                   \
        int k0_ = (KT) * 32;                                     \
        stage32(srcA + k0_, FDIM, sA[BUF], tid);                 \
        stage32(srcB + k0_, FDIM, sB[BUF], tid);                 \
    } while (0)

#define G2_COMPUTE(BUF) do {                                                  \
        bf16x8 af[4], bf[4];                                                  \
        _Pragma("unroll")                                                     \
        for (int mi = 0; mi < 4; ++mi) {                                      \
            int r = wm * 64 + mi * 16 + fr;                                   \
            af[mi] = *(const bf16x8*)((const char*)sA[BUF] + swz32(r, fq));   \
        }                                                                     \
        _Pragma("unroll")                                                     \
        for (int ni = 0; ni < 4; ++ni) {                                      \
            int r = wn * 64 + ni * 16 + fr;                                   \
            bf[ni] = *(const bf16x8*)((const char*)sB[BUF] + swz32(r, fq));   \
        }                                                                     \
        _Pragma("unroll")                                                     \
        for (int mi = 0; mi < 4; ++mi)                                        \
            _Pragma("unroll")                                                 \
            for (int ni = 0; ni < 4; ++ni)                                    \
                acc[mi][ni] = __builtin_amdgcn_mfma_f32_16x16x32_bf16(        \
                    af[mi], bf[ni], acc[mi][ni], 0, 0, 0);                    \
    } while (0)

    const int NT = FDIM / 32;          // 88, even
    G2_STAGE(0, 0);
    __syncthreads();
    for (int kt = 0; kt < NT; kt += 2) {
        G2_STAGE(1, kt + 1);
        G2_COMPUTE(0);
        __syncthreads();
        if (kt + 2 < NT) G2_STAGE(0, kt + 2);
        G2_COMPUTE(1);
        __syncthreads();
    }
#undef G2_STAGE
#undef G2_COMPUTE

#pragma unroll
    for (int mi = 0; mi < 4; ++mi) {
        int prow_b = m0 + wm * 64 + mi * 16 + fq * 4;
#pragma unroll
        for (int r = 0; r < 4; ++r) {
            int prow = prow_b + r;
            if (prow < mEnd) {
                int orow = ROUTED ? perm[prow] : prow;
#pragma unroll
                for (int ni = 0; ni < 4; ++ni) {
                    int col = n0 + wn * 64 + ni * 16 + fr;
                    float vv = acc[mi][ni][r];
                    if (ROUTED)
                        out[(size_t)orow * DDIM + col] += vv;
                    else
                        out[(size_t)orow * DDIM + col] = vv;
                }
            }
        }
    }
}

// ======================= launch =======================
extern "C" void kernel_launch(void* const* d_in, const int* in_sizes, int n_in,
                              void* d_out, int out_size, void* d_ws, size_t ws_size,
                              hipStream_t stream)
{
    const float* x      = (const float*)d_in[0];
    const float* router = (const float*)d_in[1];
    const float* w1     = (const float*)d_in[2];
    const float* w3     = (const float*)d_in[3];
    const float* w2     = (const float*)d_in[4];
    const float* ws1    = (const float*)d_in[5];
    const float* ws3    = (const float*)d_in[6];
    const float* ws2    = (const float*)d_in[7];
    float* out = (float*)d_out;

    char* ws = (char*)d_ws;
    int*   idx_a   = (int*)(ws + 0);
    float* gate_a  = (float*)(ws + 16384);
    int*   offsets = (int*)(ws + 32832);
    int*   perm    = (int*)(ws + 33280);

    bf16_t* xs    = (bf16_t*)(ws + OFF_XS);
    bf16_t* xr    = (bf16_t*)(ws + OFF_XR);
    bf16_t* mid_s = (bf16_t*)(ws + OFF_MIDS);
    bf16_t* mid_r = (bf16_t*)(ws + OFF_MIDR);
    bf16_t* w1T   = (bf16_t*)(ws + OFF_W1T);
    bf16_t* w3T   = (bf16_t*)(ws + OFF_W3T);
    bf16_t* w2T   = (bf16_t*)(ws + OFF_W2T);
    bf16_t* ws1T  = (bf16_t*)(ws + OFF_WS1T);
    bf16_t* ws3T  = (bf16_t*)(ws + OFF_WS3T);
    bf16_t* ws2T  = (bf16_t*)(ws + OFF_WS2T);

    score_kernel<<<A_TOK / 4, 256, 0, stream>>>(x, router, idx_a, gate_a);
    perm_kernel<<<1, 1024, 0, stream>>>(idx_a, offsets, perm);

    prep_x_kernel<<<A_TOK, 256, 0, stream>>>(x, gate_a, perm, xs, xr);
    tconvA_kernel<<<dim3(FDIM / 64, DDIM / 64, 18), 256, 0, stream>>>(
        w1, w3, ws1, ws3, w1T, w3T, ws1T, ws3T);

    gemm1_bf16<<<dim3(FDIM / 128, 32, NEXP + 1), 256, 0, stream>>>(
        xr, xs, w1T, w3T, ws1T, ws3T, offsets, mid_r, mid_s);

    tconvB_kernel<<<dim3(DDIM / 64, FDIM / 64, 9), 256, 0, stream>>>(
        w2, ws2, w2T, ws2T);

    gemm2_bf16<false><<<dim3(DDIM / 128, 32, 1), 256, 0, stream>>>(
        mid_s, ws2T, perm, offsets, out);
    gemm2_bf16<true><<<dim3(DDIM / 128, 32, NEXP), 256, 0, stream>>>(
        mid_r, w2T, perm, offsets, out);
}

// Round 5
// 395.078 us; speedup vs baseline: 1.1299x; 1.1299x over previous
//
#include <hip/hip_runtime.h>
#include <hip/hip_bf16.h>
#include <math.h>

#define A_TOK 4096
#define DDIM  1024
#define NEXP  8
#define FDIM  2816

typedef __bf16 bf16_t;
typedef __bf16 bf16x8 __attribute__((ext_vector_type(8)));
typedef __bf16 bf16x4 __attribute__((ext_vector_type(4)));
typedef float  f32x4  __attribute__((ext_vector_type(4)));

// ======================= workspace layout =======================
//   [0,16384)      int   idx_a[4096]
//   [16384,32768)  float gate_a[4096]
//   [32832,32868)  int   offsets[9]
//   [33280,49664)  int   perm[4096]
static constexpr size_t OFF_XS   = 65536;
static constexpr size_t OFF_XR   = OFF_XS   + (size_t)A_TOK * DDIM * 2;
static constexpr size_t OFF_MIDS = OFF_XR   + (size_t)(A_TOK + 128) * DDIM * 2;
static constexpr size_t OFF_MIDR = OFF_MIDS + (size_t)A_TOK * FDIM * 2;
static constexpr size_t OFF_W1T  = OFF_MIDR + (size_t)(A_TOK + 128) * FDIM * 2;
static constexpr size_t OFF_W3T  = OFF_W1T  + (size_t)NEXP * DDIM * FDIM * 2;
static constexpr size_t OFF_W2T  = OFF_W3T  + (size_t)NEXP * DDIM * FDIM * 2;
static constexpr size_t OFF_WS1T = OFF_W2T  + (size_t)NEXP * DDIM * FDIM * 2;
static constexpr size_t OFF_WS3T = OFF_WS1T + (size_t)DDIM * FDIM * 2;
static constexpr size_t OFF_WS2T = OFF_WS3T + (size_t)DDIM * FDIM * 2;
static constexpr size_t WS_NEED  = OFF_WS2T + (size_t)DDIM * FDIM * 2;   // ~209.5 MiB

// ======================= router: scores =======================
__global__ __launch_bounds__(256)
void score_kernel(const float* __restrict__ x,
                  const float* __restrict__ router,
                  int* __restrict__ idx_a,
                  float* __restrict__ gate_a)
{
    __shared__ float rT[NEXP][DDIM];
    const int tid = threadIdx.x;
    for (int i = tid; i < DDIM * NEXP; i += 256)
        rT[i & 7][i >> 3] = router[i];
    __syncthreads();

    const int wid = tid >> 6, lane = tid & 63;
    const int t = blockIdx.x * 4 + wid;
    const float* xr = x + (size_t)t * DDIM;

    double s[NEXP];
#pragma unroll
    for (int e = 0; e < NEXP; ++e) s[e] = 0.0;
#pragma unroll
    for (int i = 0; i < DDIM / 64; ++i) {
        int d = i * 64 + lane;
        float xv = xr[d];
#pragma unroll
        for (int e = 0; e < NEXP; ++e)
            s[e] += (double)xv * (double)rT[e][d];
    }
#pragma unroll
    for (int e = 0; e < NEXP; ++e) {
#pragma unroll
        for (int off = 32; off > 0; off >>= 1)
            s[e] += __shfl_xor(s[e], off);
    }
    if (lane == 0) {
        int best = 0; double bv = s[0];
#pragma unroll
        for (int e = 1; e < NEXP; ++e)
            if (s[e] > bv) { bv = s[e]; best = e; }
        idx_a[t] = best;
        gate_a[t] = 1.0f / (1.0f + expf(-(float)bv));
    }
}

// ======================= fused count + scan + scatter =======================
__global__ __launch_bounds__(1024)
void perm_kernel(const int* __restrict__ idx_a,
                 int* __restrict__ offsets,
                 int* __restrict__ perm)
{
    __shared__ int cnt[NEXP];
    __shared__ int base[NEXP];
    const int tid = threadIdx.x;
    if (tid < NEXP) cnt[tid] = 0;
    __syncthreads();

    int e[4];
#pragma unroll
    for (int j = 0; j < 4; ++j) {
        e[j] = idx_a[j * 1024 + tid];
        atomicAdd(&cnt[e[j]], 1);
    }
    __syncthreads();
    if (tid == 0) {
        int acc = 0;
#pragma unroll
        for (int k = 0; k < NEXP; ++k) {
            base[k] = acc; offsets[k] = acc; acc += cnt[k];
        }
        offsets[NEXP] = acc;
    }
    __syncthreads();
#pragma unroll
    for (int j = 0; j < 4; ++j) {
        int t = j * 1024 + tid;
        int pos = atomicAdd(&base[e[j]], 1);
        perm[pos] = t;
    }
}

// ======================= prep kernels =======================
__global__ void prep_x_kernel(const float* __restrict__ x,
                              const float* __restrict__ gate_a,
                              const int* __restrict__ perm,
                              bf16_t* __restrict__ xs,
                              bf16_t* __restrict__ xr)
{
    const int p = blockIdx.x;
    const int d = threadIdx.x * 4;
    float4 v = *(const float4*)(x + (size_t)p * DDIM + d);
    bf16x4 o;
    o[0] = (bf16_t)v.x; o[1] = (bf16_t)v.y; o[2] = (bf16_t)v.z; o[3] = (bf16_t)v.w;
    *(bf16x4*)(xs + (size_t)p * DDIM + d) = o;

    const int tok = perm[p];
    const float g = gate_a[tok];
    float4 w = *(const float4*)(x + (size_t)tok * DDIM + d);
    bf16x4 o2;
    o2[0] = (bf16_t)(w.x * g); o2[1] = (bf16_t)(w.y * g);
    o2[2] = (bf16_t)(w.z * g); o2[3] = (bf16_t)(w.w * g);
    *(bf16x4*)(xr + (size_t)p * DDIM + d) = o2;
}

// transpose+convert core: src [R][C] fp32 -> dst [C][R] bf16, one 64x64 tile
__device__ __forceinline__ void tconv_tile(const float* __restrict__ src,
                                           bf16_t* __restrict__ dst,
                                           int R, int C, int r0, int c0)
{
    __shared__ __align__(16) bf16_t t[64][72];
    const int tid = threadIdx.x;
    const int rl = tid >> 4;
    const int cl = (tid & 15) * 4;
#pragma unroll
    for (int i = 0; i < 4; ++i) {
        float4 v = *(const float4*)(src + (size_t)(r0 + rl + i * 16) * C + c0 + cl);
        t[cl + 0][rl + i * 16] = (bf16_t)v.x;
        t[cl + 1][rl + i * 16] = (bf16_t)v.y;
        t[cl + 2][rl + i * 16] = (bf16_t)v.z;
        t[cl + 3][rl + i * 16] = (bf16_t)v.w;
    }
    __syncthreads();
    const int cl2 = tid >> 3;
    const int rl2 = (tid & 7) * 8;
#pragma unroll
    for (int i = 0; i < 2; ++i) {
        int c = cl2 + i * 32;
        bf16x8 vv = *(const bf16x8*)&t[c][rl2];
        *(bf16x8*)(dst + (size_t)(c0 + c) * R + r0 + rl2) = vv;
    }
}

__global__ void tconvA_kernel(const float* __restrict__ w1, const float* __restrict__ w3,
                              const float* __restrict__ ws1, const float* __restrict__ ws3,
                              bf16_t* __restrict__ w1T, bf16_t* __restrict__ w3T,
                              bf16_t* __restrict__ ws1T, bf16_t* __restrict__ ws3T)
{
    const int z = blockIdx.z;
    const size_t ms = (size_t)DDIM * FDIM;
    const float* src; bf16_t* dst;
    if (z < 8)       { src = w1 + (size_t)z * ms;       dst = w1T + (size_t)z * ms; }
    else if (z < 16) { src = w3 + (size_t)(z - 8) * ms; dst = w3T + (size_t)(z - 8) * ms; }
    else if (z == 16){ src = ws1;                        dst = ws1T; }
    else             { src = ws3;                        dst = ws3T; }
    tconv_tile(src, dst, DDIM, FDIM, blockIdx.y * 64, blockIdx.x * 64);
}

__global__ void tconvB_kernel(const float* __restrict__ w2, const float* __restrict__ ws2,
                              bf16_t* __restrict__ w2T, bf16_t* __restrict__ ws2T)
{
    const int z = blockIdx.z;
    const size_t ms = (size_t)DDIM * FDIM;
    const float* src; bf16_t* dst;
    if (z < 8) { src = w2 + (size_t)z * ms; dst = w2T + (size_t)z * ms; }
    else       { src = ws2;                  dst = ws2T; }
    tconv_tile(src, dst, FDIM, DDIM, blockIdx.y * 64, blockIdx.x * 64);
}

// ======================= bf16 GEMM machinery =======================
__device__ __forceinline__ void glds16(const bf16_t* g, bf16_t* l)
{
    __builtin_amdgcn_global_load_lds(
        (const __attribute__((address_space(1))) void*)g,
        (__attribute__((address_space(3))) void*)l, 16, 0, 0);
}

// stage 128 rows x 64 bf16 (128B/row), XOR-swizzled on 16B slots (8 slots/row):
// LDS[row][slot] = global[row][slot ^ (row&7)]   -- measured 0 bank conflicts (R3)
__device__ __forceinline__ void stage_swz(const bf16_t* __restrict__ src,
                                          size_t stride, bf16_t* lds, int tid)
{
#pragma unroll
    for (int i = 0; i < 4; ++i) {
        int o = i * 256 + tid;
        int row = o >> 3;
        int slot = o & 7;
        int srcSlot = slot ^ (row & 7);
        glds16(src + (size_t)row * stride + srcSlot * 8, lds + (size_t)o * 8);
    }
}

__device__ __forceinline__ int swz_off(int row, int g16)
{
    return row * 128 + ((g16 ^ (row & 7)) << 4);
}

// XCD-chunked remap for gemm1 (704 blocks, %8==0): within an XCD, m-blocks
// iterate fastest -> the 512KB B-panel pair stays hot in that XCD's L2.
// Measured R4: FETCH_SIZE 292MB -> 152MB.
__device__ __forceinline__ void remap_nm(int& nb, int& mb)
{
    int lin = blockIdx.x + blockIdx.y * gridDim.x;
    int cpx = (gridDim.x * gridDim.y) >> 3;
    int w = (lin & 7) * cpx + (lin >> 3);
    nb = w >> 5;        // / 32 m-blocks
    mb = w & 31;        // % 32
}

// GEMM1: mid = silu(A@W1T^T) * (A@W3T^T); 128x128 tile, BK=64, single buffer
__global__ __launch_bounds__(256, 2)
void gemm1_bf16(const bf16_t* __restrict__ xr, const bf16_t* __restrict__ xs,
                const bf16_t* __restrict__ w1T, const bf16_t* __restrict__ w3T,
                const bf16_t* __restrict__ ws1T, const bf16_t* __restrict__ ws3T,
                const int* __restrict__ offsets,
                bf16_t* __restrict__ mid_r, bf16_t* __restrict__ mid_s)
{
    int nb, mb;
    remap_nm(nb, mb);
    const int g  = blockIdx.z;
    const int n0 = nb * 128;
    int m0, mEnd;
    const bf16_t *pa, *pw1, *pw3;
    bf16_t* pout;
    if (g < NEXP) {
        int s = offsets[g], e = offsets[g + 1];
        m0 = s + mb * 128;
        if (m0 >= e) return;
        mEnd = e;
        pa = xr;
        pw1 = w1T + (size_t)g * DDIM * FDIM;
        pw3 = w3T + (size_t)g * DDIM * FDIM;
        pout = mid_r;
    } else {
        m0 = mb * 128;
        mEnd = A_TOK;
        pa = xs; pw1 = ws1T; pw3 = ws3T; pout = mid_s;
    }

    __shared__ __align__(16) bf16_t sA[128 * 64];
    __shared__ __align__(16) bf16_t sB1[128 * 64];
    __shared__ __align__(16) bf16_t sB3[128 * 64];

    const int tid  = threadIdx.x;
    const int lane = tid & 63;
    const int wid  = tid >> 6;
    const int wm   = wid >> 1, wn = wid & 1;
    const int fr   = lane & 15;
    const int fq   = lane >> 4;

    f32x4 acc1[4][4], acc3[4][4];
#pragma unroll
    for (int i = 0; i < 4; ++i)
#pragma unroll
        for (int j = 0; j < 4; ++j) {
            acc1[i][j] = (f32x4){0.f, 0.f, 0.f, 0.f};
            acc3[i][j] = (f32x4){0.f, 0.f, 0.f, 0.f};
        }

    const bf16_t* srcA  = pa  + (size_t)m0 * DDIM;
    const bf16_t* srcB1 = pw1 + (size_t)n0 * DDIM;
    const bf16_t* srcB3 = pw3 + (size_t)n0 * DDIM;

    for (int k0 = 0; k0 < DDIM; k0 += 64) {
        stage_swz(srcA  + k0, DDIM, sA,  tid);
        stage_swz(srcB1 + k0, DDIM, sB1, tid);
        stage_swz(srcB3 + k0, DDIM, sB3, tid);
        __syncthreads();

#pragma unroll
        for (int s = 0; s < 2; ++s) {
            const int kg = s * 4 + fq;
            bf16x8 af[4], b1f[4], b3f[4];
#pragma unroll
            for (int mi = 0; mi < 4; ++mi) {
                int r = wm * 64 + mi * 16 + fr;
                af[mi] = *(const bf16x8*)((const char*)sA + swz_off(r, kg));
            }
#pragma unroll
            for (int ni = 0; ni < 4; ++ni) {
                int r = wn * 64 + ni * 16 + fr;
                b1f[ni] = *(const bf16x8*)((const char*)sB1 + swz_off(r, kg));
                b3f[ni] = *(const bf16x8*)((const char*)sB3 + swz_off(r, kg));
            }
#pragma unroll
            for (int mi = 0; mi < 4; ++mi)
#pragma unroll
                for (int ni = 0; ni < 4; ++ni) {
                    acc1[mi][ni] = __builtin_amdgcn_mfma_f32_16x16x32_bf16(af[mi], b1f[ni], acc1[mi][ni], 0, 0, 0);
                    acc3[mi][ni] = __builtin_amdgcn_mfma_f32_16x16x32_bf16(af[mi], b3f[ni], acc3[mi][ni], 0, 0, 0);
                }
        }
        __syncthreads();
    }

#pragma unroll
    for (int mi = 0; mi < 4; ++mi) {
        int prow_b = m0 + wm * 64 + mi * 16 + fq * 4;
#pragma unroll
        for (int r = 0; r < 4; ++r) {
            int prow = prow_b + r;
            if (prow < mEnd) {
#pragma unroll
                for (int ni = 0; ni < 4; ++ni) {
                    float h1 = acc1[mi][ni][r];
                    float h3 = acc3[mi][ni][r];
                    float vv = h1 / (1.0f + __expf(-h1)) * h3;
                    int col = n0 + wn * 64 + ni * 16 + fr;
                    pout[(size_t)prow * FDIM + col] = (bf16_t)vv;
                }
            }
        }
    }
}

// GEMM2: out = mid @ W2; 128x128 tile, BK=64, single buffer (round-3 exact)
template <bool ROUTED>
__global__ __launch_bounds__(256, 2)
void gemm2_bf16(const bf16_t* __restrict__ mid, const bf16_t* __restrict__ w2T,
                const int* __restrict__ perm, const int* __restrict__ offsets,
                float* __restrict__ out)
{
    const int n0 = blockIdx.x * 128;
    int m0, mEnd;
    const bf16_t* pb;
    if (ROUTED) {
        int g = blockIdx.z;
        int s = offsets[g], e = offsets[g + 1];
        m0 = s + blockIdx.y * 128;
        if (m0 >= e) return;
        mEnd = e;
        pb = w2T + (size_t)g * DDIM * FDIM;
    } else {
        m0 = blockIdx.y * 128;
        mEnd = A_TOK;
        pb = w2T;
    }

    __shared__ __align__(16) bf16_t sA[128 * 64];
    __shared__ __align__(16) bf16_t sB[128 * 64];

    const int tid  = threadIdx.x;
    const int lane = tid & 63;
    const int wid  = tid >> 6;
    const int wm   = wid >> 1, wn = wid & 1;
    const int fr   = lane & 15;
    const int fq   = lane >> 4;

    f32x4 acc[4][4];
#pragma unroll
    for (int i = 0; i < 4; ++i)
#pragma unroll
        for (int j = 0; j < 4; ++j)
            acc[i][j] = (f32x4){0.f, 0.f, 0.f, 0.f};

    const bf16_t* srcA = mid + (size_t)m0 * FDIM;
    const bf16_t* srcB = pb  + (size_t)n0 * FDIM;

    for (int k0 = 0; k0 < FDIM; k0 += 64) {
        stage_swz(srcA + k0, FDIM, sA, tid);
        stage_swz(srcB + k0, FDIM, sB, tid);
        __syncthreads();

#pragma unroll
        for (int s = 0; s < 2; ++s) {
            const int kg = s * 4 + fq;
            bf16x8 af[4], bf[4];
#pragma unroll
            for (int mi = 0; mi < 4; ++mi) {
                int r = wm * 64 + mi * 16 + fr;
                af[mi] = *(const bf16x8*)((const char*)sA + swz_off(r, kg));
            }
#pragma unroll
            for (int ni = 0; ni < 4; ++ni) {
                int r = wn * 64 + ni * 16 + fr;
                bf[ni] = *(const bf16x8*)((const char*)sB + swz_off(r, kg));
            }
#pragma unroll
            for (int mi = 0; mi < 4; ++mi)
#pragma unroll
                for (int ni = 0; ni < 4; ++ni)
                    acc[mi][ni] = __builtin_amdgcn_mfma_f32_16x16x32_bf16(af[mi], bf[ni], acc[mi][ni], 0, 0, 0);
        }
        __syncthreads();
    }

#pragma unroll
    for (int mi = 0; mi < 4; ++mi) {
        int prow_b = m0 + wm * 64 + mi * 16 + fq * 4;
#pragma unroll
        for (int r = 0; r < 4; ++r) {
            int prow = prow_b + r;
            if (prow < mEnd) {
                int orow = ROUTED ? perm[prow] : prow;
#pragma unroll
                for (int ni = 0; ni < 4; ++ni) {
                    int col = n0 + wn * 64 + ni * 16 + fr;
                    float vv = acc[mi][ni][r];
                    if (ROUTED)
                        out[(size_t)orow * DDIM + col] += vv;
                    else
                        out[(size_t)orow * DDIM + col] = vv;
                }
            }
        }
    }
}

// ======================= launch =======================
extern "C" void kernel_launch(void* const* d_in, const int* in_sizes, int n_in,
                              void* d_out, int out_size, void* d_ws, size_t ws_size,
                              hipStream_t stream)
{
    const float* x      = (const float*)d_in[0];
    const float* router = (const float*)d_in[1];
    const float* w1     = (const float*)d_in[2];
    const float* w3     = (const float*)d_in[3];
    const float* w2     = (const float*)d_in[4];
    const float* ws1    = (const float*)d_in[5];
    const float* ws3    = (const float*)d_in[6];
    const float* ws2    = (const float*)d_in[7];
    float* out = (float*)d_out;

    char* ws = (char*)d_ws;
    int*   idx_a   = (int*)(ws + 0);
    float* gate_a  = (float*)(ws + 16384);
    int*   offsets = (int*)(ws + 32832);
    int*   perm    = (int*)(ws + 33280);

    bf16_t* xs    = (bf16_t*)(ws + OFF_XS);
    bf16_t* xr    = (bf16_t*)(ws + OFF_XR);
    bf16_t* mid_s = (bf16_t*)(ws + OFF_MIDS);
    bf16_t* mid_r = (bf16_t*)(ws + OFF_MIDR);
    bf16_t* w1T   = (bf16_t*)(ws + OFF_W1T);
    bf16_t* w3T   = (bf16_t*)(ws + OFF_W3T);
    bf16_t* w2T   = (bf16_t*)(ws + OFF_W2T);
    bf16_t* ws1T  = (bf16_t*)(ws + OFF_WS1T);
    bf16_t* ws3T  = (bf16_t*)(ws + OFF_WS3T);
    bf16_t* ws2T  = (bf16_t*)(ws + OFF_WS2T);

    score_kernel<<<A_TOK / 4, 256, 0, stream>>>(x, router, idx_a, gate_a);
    perm_kernel<<<1, 1024, 0, stream>>>(idx_a, offsets, perm);

    prep_x_kernel<<<A_TOK, 256, 0, stream>>>(x, gate_a, perm, xs, xr);
    tconvA_kernel<<<dim3(FDIM / 64, DDIM / 64, 18), 256, 0, stream>>>(
        w1, w3, ws1, ws3, w1T, w3T, ws1T, ws3T);

    gemm1_bf16<<<dim3(FDIM / 128, 32, NEXP + 1), 256, 0, stream>>>(
        xr, xs, w1T, w3T, ws1T, ws3T, offsets, mid_r, mid_s);

    tconvB_kernel<<<dim3(DDIM / 64, FDIM / 64, 9), 256, 0, stream>>>(
        w2, ws2, w2T, ws2T);

    gemm2_bf16<false><<<dim3(DDIM / 128, 32, 1), 256, 0, stream>>>(
        mid_s, ws2T, perm, offsets, out);
    gemm2_bf16<true><<<dim3(DDIM / 128, 32, NEXP), 256, 0, stream>>>(
        mid_r, w2T, perm, offsets, out);
}